// Round 13
// baseline (290.212 us; speedup 1.0000x reference)
//
#include <hip/hip_runtime.h>
#include <hip/hip_bf16.h>

// SpectralAttentionLayer: ChebConv(K=3) -> relu -> GATv2(heads=1)
// N=100000, E=1600000, D=32.  All float inputs f32 (device detector kept as
// insurance), output f32.
// Round-13: all randomly-gathered node tables (u-copy, X1, X2->unused, fsrc)
// stored bf16 -> 64-B rows, 1 cache line per edge-gather instead of 2, and
// the hot table (6.4 MB) now mostly fits one XCD L2 (4 MB).  Error budget:
// absmax 0.0078 -> ~0.02, threshold 0.0737.

typedef unsigned short u16;

#define DD 32
#define NEG_SLOPE 0.2f
#define BLK 256
#define TILE 4096            // edges per pass-1 tile
#define CB_SHIFT 8           // coarse bucket = dst >> 8 (256 nodes)
#define CB_NODES 256
#define SRC_BITS 17          // N=100000 < 2^17

// weight block offsets inside wsW (floats)
#define OFF_CHEBW 0      // 3072
#define OFF_CHEBB 3072   // 32
#define OFF_SRCW  3104   // 1024
#define OFF_SRCB  4128   // 32
#define OFF_DSTW  4160   // 1024
#define OFF_DSTB  5184   // 32
#define OFF_ATTN  5216   // 32
#define OFF_LMAX  5248   // 1
#define W_TOTAL   5249

// flags indices (1 = f32 storage, 0 = bf16 storage)
#define F_U     0
#define F_CHEBW 1
#define F_CHEBB 2
#define F_SRCW  3
#define F_SRCB  4
#define F_DSTW  5
#define F_DSTB  6
#define F_ATTN  7
#define F_LMAX  8
#define N_FLAGS 9

__device__ __forceinline__ float bh2f(u16 h) {
    return __uint_as_float(((unsigned)h) << 16);
}
// round-to-nearest-even f32 -> bf16 bits
__device__ __forceinline__ u16 f2b(float v) {
    unsigned x = __float_as_uint(v);
    return (u16)((x + 0x7FFFu + ((x >> 16) & 1u)) >> 16);
}
__device__ __forceinline__ float rdin(const void* p, long long i, int f32f) {
    return f32f ? ((const float*)p)[i] : bh2f(((const u16*)p)[i]);
}
__device__ __forceinline__ float4 rd4(const void* p, long long row, int q, int f32f) {
    if (f32f) return ((const float4*)p)[row * 8 + q];
    ushort4 h = ((const ushort4*)p)[row * 8 + q];
    return make_float4(bh2f(h.x), bh2f(h.y), bh2f(h.z), bh2f(h.w));
}
// bf16 row table: float4 group q (dims 4q..4q+3) of row
__device__ __forceinline__ float4 rb4(const u16* p, long long row, int q) {
    ushort4 h = ((const ushort4*)p)[row * 8 + q];
    return make_float4(bh2f(h.x), bh2f(h.y), bh2f(h.z), bh2f(h.w));
}
__device__ __forceinline__ ushort4 pk4(float a, float b, float c, float d) {
    ushort4 r; r.x = f2b(a); r.y = f2b(b); r.z = f2b(c); r.w = f2b(d);
    return r;
}
__device__ __forceinline__ float lrelu(float x) { return fmaxf(x, NEG_SLOPE * x); }

__device__ __forceinline__ int plaus(u16 h) {
    if ((h & 0x7FFFu) == 0) return 1;
    unsigned e = (h >> 7) & 0xFF;
    return (e >= 0x60 && e <= 0x8F) ? 1 : 0;
}

// one block per array; 64 threads vote on even halfwords
__global__ void k_detect(const void* p0, const void* p1, const void* p2,
                         const void* p3, const void* p4, const void* p5,
                         const void* p6, const void* p7, const void* p8,
                         int n0, int n7, int* __restrict__ flags) {
    __shared__ int cEven, cEvenZ, cOddNZ;
    const void* ptrs[N_FLAGS] = {p0, p1, p2, p3, p4, p5, p6, p7, p8};
    const int   ns[N_FLAGS]   = {n0, 3072, 32, 1024, 32, 1024, 32, n7, 1};
    int a = blockIdx.x;
    if (a >= N_FLAGS) return;
    const u16* h = (const u16*)ptrs[a];
    int n = ns[a];
    if (threadIdx.x == 0) { cEven = 0; cEvenZ = 0; cOddNZ = 0; }
    __syncthreads();
    if (n == 1) {
        if (threadIdx.x == 0) {
            u16 v = h[0];
            flags[a] = ((v & 0x7FFFu) == 0 || !plaus(v)) ? 1 : 0;
        }
        return;
    }
    int nprobe = n >> 1;
    if (nprobe > 64) nprobe = 64;
    int t = threadIdx.x;
    if (t < nprobe) {
        u16 ev = h[2 * t];
        u16 od = h[2 * t + 1];
        if (plaus(ev)) atomicAdd(&cEven, 1);
        if ((ev & 0x7FFFu) == 0) atomicAdd(&cEvenZ, 1);
        if (plaus(od) && (od & 0x7FFFu) != 0) atomicAdd(&cOddNZ, 1);
    }
    __syncthreads();
    if (threadIdx.x == 0) {
        int bf = (cEven * 4 >= nprobe * 3);
        if (cEvenZ == nprobe && cOddNZ * 2 >= nprobe) bf = 0;
        flags[a] = bf ? 0 : 1;
    }
}

// converts weights into fp32 wsW; also zeroes Mabs (last 32 slots)
__global__ void k_cvtw(const void* chebW, const void* chebB, const void* srcW,
                       const void* srcB, const void* dstW, const void* dstB,
                       const void* attn, const void* lmax,
                       const int* __restrict__ flags, float* __restrict__ wsW,
                       unsigned* __restrict__ Mabs) {
    int i = blockIdx.x * blockDim.x + threadIdx.x;
    if (i >= W_TOTAL + 32) return;
    if (i >= W_TOTAL) { Mabs[i - W_TOTAL] = 0u; return; }
    float v;
    if      (i < OFF_CHEBB) v = rdin(chebW, i - OFF_CHEBW, flags[F_CHEBW]);
    else if (i < OFF_SRCW)  v = rdin(chebB, i - OFF_CHEBB, flags[F_CHEBB]);
    else if (i < OFF_SRCB)  v = rdin(srcW,  i - OFF_SRCW,  flags[F_SRCW]);
    else if (i < OFF_DSTW)  v = rdin(srcB,  i - OFF_SRCB,  flags[F_SRCB]);
    else if (i < OFF_DSTB)  v = rdin(dstW,  i - OFF_DSTW,  flags[F_DSTW]);
    else if (i < OFF_ATTN)  v = rdin(dstB,  i - OFF_DSTB,  flags[F_DSTB]);
    else if (i < OFF_LMAX)  v = rdin(attn,  i - OFF_ATTN,  flags[F_ATTN]);
    else                    v = rdin(lmax,  0,             flags[F_LMAX]);
    wsW[i] = v;
}

// u -> bf16 copy (the unnl1 gather table)
__global__ void k_cvtu(const void* __restrict__ u, const int* __restrict__ flags,
                       u16* __restrict__ ub, int ND) {
    int i = blockIdx.x * blockDim.x + threadIdx.x;
    if (i < ND) ub[i] = f2b(rdin(u, i, flags[F_U]));
}

// ---------------- two-level counting sort ----------------

__global__ __launch_bounds__(BLK) void k_h1(
        const int* __restrict__ dst, unsigned* __restrict__ hist1,
        int E, int T, int NB1) {
    __shared__ unsigned lh[512];
    int tile = blockIdx.x, t = threadIdx.x;
    for (int b = t; b < 512; b += BLK) lh[b] = 0;
    __syncthreads();
    int base = tile * TILE;
    for (int i = 0; i < TILE / BLK; i++) {
        int e = base + i * BLK + t;
        if (e < E) atomicAdd(&lh[dst[e] >> CB_SHIFT], 1u);
    }
    __syncthreads();
    for (int b = t; b < NB1; b += BLK) hist1[(size_t)b * T + tile] = lh[b];
}

__global__ __launch_bounds__(BLK) void k_scA(
        unsigned* __restrict__ h, unsigned* __restrict__ bsum, int T) {
    __shared__ unsigned s[BLK];
    int b = blockIdx.x, t = threadIdx.x;
    unsigned carry = 0;
    for (int base = 0; base < T; base += BLK) {
        int i = base + t;
        unsigned v = (i < T) ? h[(size_t)b * T + i] : 0u;
        s[t] = v;
        __syncthreads();
        for (int off = 1; off < BLK; off <<= 1) {
            unsigned a = (t >= off) ? s[t - off] : 0u;
            __syncthreads();
            s[t] += a;
            __syncthreads();
        }
        if (i < T) h[(size_t)b * T + i] = carry + s[t] - v;
        carry += s[BLK - 1];
        __syncthreads();
    }
    if (t == 0) bsum[b] = carry;
}

__global__ __launch_bounds__(512) void k_scB(
        unsigned* __restrict__ bsum, int NB1,
        unsigned* __restrict__ row_ptr, int N, int E) {
    __shared__ unsigned s[512];
    int t = threadIdx.x;
    unsigned v = (t < NB1) ? bsum[t] : 0u;
    s[t] = v;
    __syncthreads();
    for (int off = 1; off < 512; off <<= 1) {
        unsigned a = (t >= off) ? s[t - off] : 0u;
        __syncthreads();
        s[t] += a;
        __syncthreads();
    }
    if (t < NB1) bsum[t] = s[t] - v;
    if (t == 0) row_ptr[N] = (unsigned)E;
}

__global__ __launch_bounds__(BLK) void k_s1(
        const int* __restrict__ src, const int* __restrict__ dst,
        const unsigned* __restrict__ off1, const unsigned* __restrict__ bsum,
        unsigned* __restrict__ tmp, int E, int T, int NB1) {
    __shared__ unsigned cur[512];
    int tile = blockIdx.x, t = threadIdx.x;
    for (int b = t; b < NB1; b += BLK)
        cur[b] = off1[(size_t)b * T + tile] + bsum[b];
    __syncthreads();
    int base = tile * TILE;
    for (int i = 0; i < TILE / BLK; i++) {
        int e = base + i * BLK + t;
        if (e < E) {
            int d = dst[e];
            unsigned pos = atomicAdd(&cur[d >> CB_SHIFT], 1u);
            tmp[pos] = ((unsigned)(d & (CB_NODES - 1)) << SRC_BITS) | (unsigned)src[e];
        }
    }
}

__global__ __launch_bounds__(BLK) void k_p2(
        const unsigned* __restrict__ tmp, const unsigned* __restrict__ bsum,
        unsigned* __restrict__ row_ptr, float* __restrict__ dinv,
        int* __restrict__ srcs, int N, int E, int T, int NB1) {
    __shared__ unsigned hist[CB_NODES], cur[CB_NODES], ssc[BLK];
    int b = blockIdx.x, t = threadIdx.x;
    int nodeBase = b << CB_SHIFT;
    unsigned lo = bsum[b];
    unsigned hi = (b + 1 < NB1) ? bsum[b + 1] : (unsigned)E;
    hist[t] = 0;
    __syncthreads();
    for (unsigned e = lo + t; e < hi; e += BLK)
        atomicAdd(&hist[tmp[e] >> SRC_BITS], 1u);
    __syncthreads();
    unsigned v = hist[t];
    ssc[t] = v;
    __syncthreads();
    for (int off = 1; off < BLK; off <<= 1) {
        unsigned a = (t >= off) ? ssc[t - off] : 0u;
        __syncthreads();
        ssc[t] += a;
        __syncthreads();
    }
    unsigned ex = ssc[t] - v;
    cur[t] = ex;
    int node = nodeBase + t;
    if (node < N) {
        row_ptr[node] = lo + ex;
        unsigned c = v;
        if (c < 1u) c = 1u;
        dinv[node] = rsqrtf((float)c);
    }
    __syncthreads();
    for (unsigned e = lo + t; e < hi; e += BLK) {
        unsigned p = tmp[e];
        unsigned pos = lo + atomicAdd(&cur[p >> SRC_BITS], 1u);
        srcs[pos] = (int)(p & ((1u << SRC_BITS) - 1u));
    }
}

// ---------------- wave-per-node gather kernels (bf16 tables, 32-edge) ------

__global__ __launch_bounds__(BLK) void k_unnl1(
        const u16* __restrict__ ub, const void* __restrict__ u,
        const int* __restrict__ flags, const float* __restrict__ dinv,
        const unsigned* __restrict__ row_ptr, const int* __restrict__ srcs,
        const float* __restrict__ wsW, u16* __restrict__ X1b, int N) {
    int wave = (blockIdx.x * BLK + threadIdx.x) >> 6;
    if (wave >= N) return;
    int lane = threadIdx.x & 63, q = lane & 7, g = lane >> 3;
    int base = (int)row_ptr[wave], end = (int)row_ptr[wave + 1];
    float4 acc = make_float4(0.f, 0.f, 0.f, 0.f);
    for (int i = base; i < end; i += 32) {
        int e0 = i + g, e1 = i + 8 + g, e2 = i + 16 + g, e3 = i + 24 + g;
        int s0 = srcs[min(e0, end - 1)], s1 = srcs[min(e1, end - 1)];
        int s2 = srcs[min(e2, end - 1)], s3 = srcs[min(e3, end - 1)];
        float dv0 = dinv[s0], dv1 = dinv[s1], dv2 = dinv[s2], dv3 = dinv[s3];
        if (e0 >= end) dv0 = 0.f;
        if (e1 >= end) dv1 = 0.f;
        if (e2 >= end) dv2 = 0.f;
        if (e3 >= end) dv3 = 0.f;
        float4 x0 = rb4(ub, s0, q);
        float4 x1 = rb4(ub, s1, q);
        float4 x2 = rb4(ub, s2, q);
        float4 x3 = rb4(ub, s3, q);
        acc.x += x0.x * dv0 + x1.x * dv1 + x2.x * dv2 + x3.x * dv3;
        acc.y += x0.y * dv0 + x1.y * dv1 + x2.y * dv2 + x3.y * dv3;
        acc.z += x0.z * dv0 + x1.z * dv1 + x2.z * dv2 + x3.z * dv3;
        acc.w += x0.w * dv0 + x1.w * dv1 + x2.w * dv2 + x3.w * dv3;
    }
#pragma unroll
    for (int off = 8; off <= 32; off <<= 1) {
        acc.x += __shfl_xor(acc.x, off);
        acc.y += __shfl_xor(acc.y, off);
        acc.z += __shfl_xor(acc.z, off);
        acc.w += __shfl_xor(acc.w, off);
    }
    if (g == 0) {
        float rn = 2.0f / wsW[OFF_LMAX];
        float dn = dinv[wave];
        float4 x0 = rd4(u, wave, q, flags[F_U]);    // f32 input for precision
        ((ushort4*)X1b)[(size_t)wave * 8 + q] =
            pk4(-rn * (acc.x * dn) + x0.x * (rn - 1.f),
                -rn * (acc.y * dn) + x0.y * (rn - 1.f),
                -rn * (acc.z * dn) + x0.z * (rn - 1.f),
                -rn * (acc.w * dn) + x0.w * (rn - 1.f));
    }
}

__global__ __launch_bounds__(BLK) void k_unnl2(
        const u16* __restrict__ X1b, const void* __restrict__ u,
        const int* __restrict__ flags, const float* __restrict__ dinv,
        const unsigned* __restrict__ row_ptr, const int* __restrict__ srcs,
        const float* __restrict__ wsW, u16* __restrict__ X2b, int N) {
    int wave = (blockIdx.x * BLK + threadIdx.x) >> 6;
    if (wave >= N) return;
    int lane = threadIdx.x & 63, q = lane & 7, g = lane >> 3;
    int base = (int)row_ptr[wave], end = (int)row_ptr[wave + 1];
    float4 acc = make_float4(0.f, 0.f, 0.f, 0.f);
    for (int i = base; i < end; i += 32) {
        int e0 = i + g, e1 = i + 8 + g, e2 = i + 16 + g, e3 = i + 24 + g;
        int s0 = srcs[min(e0, end - 1)], s1 = srcs[min(e1, end - 1)];
        int s2 = srcs[min(e2, end - 1)], s3 = srcs[min(e3, end - 1)];
        float dv0 = dinv[s0], dv1 = dinv[s1], dv2 = dinv[s2], dv3 = dinv[s3];
        if (e0 >= end) dv0 = 0.f;
        if (e1 >= end) dv1 = 0.f;
        if (e2 >= end) dv2 = 0.f;
        if (e3 >= end) dv3 = 0.f;
        float4 x0 = rb4(X1b, s0, q);
        float4 x1 = rb4(X1b, s1, q);
        float4 x2 = rb4(X1b, s2, q);
        float4 x3 = rb4(X1b, s3, q);
        acc.x += x0.x * dv0 + x1.x * dv1 + x2.x * dv2 + x3.x * dv3;
        acc.y += x0.y * dv0 + x1.y * dv1 + x2.y * dv2 + x3.y * dv3;
        acc.z += x0.z * dv0 + x1.z * dv1 + x2.z * dv2 + x3.z * dv3;
        acc.w += x0.w * dv0 + x1.w * dv1 + x2.w * dv2 + x3.w * dv3;
    }
#pragma unroll
    for (int off = 8; off <= 32; off <<= 1) {
        acc.x += __shfl_xor(acc.x, off);
        acc.y += __shfl_xor(acc.y, off);
        acc.z += __shfl_xor(acc.z, off);
        acc.w += __shfl_xor(acc.w, off);
    }
    if (g == 0) {
        float rn = 2.0f / wsW[OFF_LMAX];
        float dn = dinv[wave];
        float4 x0 = rd4(u, wave, q, flags[F_U]);
        float4 x1 = rb4(X1b, wave, q);
        ((ushort4*)X2b)[(size_t)wave * 8 + q] =
            pk4(-2.f * rn * (acc.x * dn) + x1.x * (2.f * (rn - 1.f)) - x0.x,
                -2.f * rn * (acc.y * dn) + x1.y * (2.f * (rn - 1.f)) - x0.y,
                -2.f * rn * (acc.z * dn) + x1.z * (2.f * (rn - 1.f)) - x0.z,
                -2.f * rn * (acc.w * dn) + x1.w * (2.f * (rn - 1.f)) - x0.w);
    }
}

// ---------------- fused cheb + projections, node-per-thread ----------------
// fsrcb (bf16) aliases X1b: thread reads its own X1b/X2b rows fully before
// writing its fsrcb row.  fdst goes to a separate f32 buffer (coalesced,
// read once per node in k_gat).
__global__ __launch_bounds__(BLK) void k_cfsd(
        const void* __restrict__ u, const int* __restrict__ flags,
        const u16* X1b, const u16* X2b,
        const float* __restrict__ wsW, u16* fsrcb,
        float* __restrict__ fd, unsigned* __restrict__ Mabs, int N) {
    __shared__ float sW[3072], sWs[1024], sWd[1024];
    __shared__ float sb[32], sbs[32], sbd[32];
    __shared__ float hcS[BLK * 33];          // pad 33 -> conflict-free
    __shared__ unsigned mloc[32];
    int t = threadIdx.x;
    for (int i = t; i < 3072; i += BLK) sW[i] = wsW[OFF_CHEBW + i];
    for (int i = t; i < 1024; i += BLK) {
        sWs[i] = wsW[OFF_SRCW + i];
        sWd[i] = wsW[OFF_DSTW + i];
    }
    if (t < 32) {
        sb[t]  = wsW[OFF_CHEBB + t];
        sbs[t] = wsW[OFF_SRCB + t];
        sbd[t] = wsW[OFF_DSTB + t];
        mloc[t] = 0u;
    }
    __syncthreads();
    int f = flags[F_U];
    float mabs = 0.f;
    int n = blockIdx.x * BLK + t;
    if (n < N) {
        long long row = (long long)n;
        float acc[32];
#pragma unroll
        for (int j = 0; j < 32; j++) acc[j] = sb[j];
        for (int i4 = 0; i4 < 8; i4++) {
            float4 x = rd4(u, row, i4, f);
            const float* w = &sW[i4 * 128];
#pragma unroll
            for (int j = 0; j < 32; j++) acc[j] = fmaf(x.x, w[j], acc[j]);
#pragma unroll
            for (int j = 0; j < 32; j++) acc[j] = fmaf(x.y, w[32 + j], acc[j]);
#pragma unroll
            for (int j = 0; j < 32; j++) acc[j] = fmaf(x.z, w[64 + j], acc[j]);
#pragma unroll
            for (int j = 0; j < 32; j++) acc[j] = fmaf(x.w, w[96 + j], acc[j]);
        }
        for (int i4 = 0; i4 < 8; i4++) {
            float4 x = rb4(X1b, row, i4);
            const float* w = &sW[1024 + i4 * 128];
#pragma unroll
            for (int j = 0; j < 32; j++) acc[j] = fmaf(x.x, w[j], acc[j]);
#pragma unroll
            for (int j = 0; j < 32; j++) acc[j] = fmaf(x.y, w[32 + j], acc[j]);
#pragma unroll
            for (int j = 0; j < 32; j++) acc[j] = fmaf(x.z, w[64 + j], acc[j]);
#pragma unroll
            for (int j = 0; j < 32; j++) acc[j] = fmaf(x.w, w[96 + j], acc[j]);
        }
        for (int i4 = 0; i4 < 8; i4++) {
            float4 x = rb4(X2b, row, i4);
            const float* w = &sW[2048 + i4 * 128];
#pragma unroll
            for (int j = 0; j < 32; j++) acc[j] = fmaf(x.x, w[j], acc[j]);
#pragma unroll
            for (int j = 0; j < 32; j++) acc[j] = fmaf(x.y, w[32 + j], acc[j]);
#pragma unroll
            for (int j = 0; j < 32; j++) acc[j] = fmaf(x.z, w[64 + j], acc[j]);
#pragma unroll
            for (int j = 0; j < 32; j++) acc[j] = fmaf(x.w, w[96 + j], acc[j]);
        }
#pragma unroll
        for (int j = 0; j < 32; j++) hcS[t * 33 + j] = fmaxf(acc[j], 0.f);
        float as[32], ad[32];
#pragma unroll
        for (int j = 0; j < 32; j++) { as[j] = sbs[j]; ad[j] = sbd[j]; }
        for (int i = 0; i < 32; i++) {
            float hv = hcS[t * 33 + i];
            const float* ws = &sWs[i * 32];
            const float* wd = &sWd[i * 32];
#pragma unroll
            for (int j = 0; j < 32; j++) {
                as[j] = fmaf(hv, ws[j], as[j]);
                ad[j] = fmaf(hv, wd[j], ad[j]);
            }
        }
        ushort4* fs4 = (ushort4*)(fsrcb + row * 32);
        float4*  fd4 = (float4*)(fd + row * 32);
#pragma unroll
        for (int i4 = 0; i4 < 8; i4++) {
            fs4[i4] = pk4(as[4 * i4], as[4 * i4 + 1], as[4 * i4 + 2], as[4 * i4 + 3]);
            fd4[i4] = make_float4(ad[4 * i4], ad[4 * i4 + 1], ad[4 * i4 + 2], ad[4 * i4 + 3]);
        }
#pragma unroll
        for (int j = 0; j < 32; j++) mabs = fmaxf(mabs, fabsf(as[j]));
    }
    // mabs = node max over all dims; per-dim max <= this, so K from Mabs
    // remains a valid upper bound (bf16 round-up of fsrc adds < 0.4% which
    // is covered by the node-max slack).
    atomicMax(&mloc[t & 31], __float_as_uint(mabs * 1.01f));
    __syncthreads();
    if (t < 32) atomicMax(&Mabs[t], mloc[t]);
}

// ---------------- fused GATv2, bound-shifted softmax, single pass ----------
__global__ __launch_bounds__(BLK) void k_gat(
        const u16* __restrict__ fsrcb, const float* __restrict__ fd,
        const unsigned* __restrict__ row_ptr, const int* __restrict__ srcs,
        const float* __restrict__ wsW, const unsigned* __restrict__ Mabs,
        float* __restrict__ out, int N) {
    int wave = (blockIdx.x * BLK + threadIdx.x) >> 6;
    if (wave >= N) return;
    int lane = threadIdx.x & 63, q = lane & 7, g = lane >> 3;
    int base = (int)row_ptr[wave], end = (int)row_ptr[wave + 1];
    if (base == end) {
        if (g == 0)
            ((float4*)out)[(size_t)wave * 8 + q] = make_float4(0.f, 0.f, 0.f, 0.f);
        return;
    }
    float4 fdv = ((const float4*)fd)[(size_t)wave * 8 + q];
    float4 at = ((const float4*)(wsW + OFF_ATTN))[q];
    float4 mb = ((const float4*)Mabs)[q];   // bits of nonneg floats
    float kp = (mb.x + fabsf(fdv.x)) * fabsf(at.x) +
               (mb.y + fabsf(fdv.y)) * fabsf(at.y) +
               (mb.z + fabsf(fdv.z)) * fabsf(at.z) +
               (mb.w + fabsf(fdv.w)) * fabsf(at.w);
    kp += __shfl_xor(kp, 1);
    kp += __shfl_xor(kp, 2);
    kp += __shfl_xor(kp, 4);
    float K = kp;
    float4 acc = make_float4(0.f, 0.f, 0.f, 0.f);
    float den = 0.f;
    for (int i = base; i < end; i += 16) {
        int e0 = i + g, e1 = i + 8 + g;
        int ec0 = min(e0, end - 1), ec1 = min(e1, end - 1);
        int s0 = srcs[ec0], s1 = srcs[ec1];
        float4 fs0 = rb4(fsrcb, s0, q);
        float4 fs1 = rb4(fsrcb, s1, q);
        float v0 = lrelu(fs0.x + fdv.x) * at.x + lrelu(fs0.y + fdv.y) * at.y +
                   lrelu(fs0.z + fdv.z) * at.z + lrelu(fs0.w + fdv.w) * at.w;
        float v1 = lrelu(fs1.x + fdv.x) * at.x + lrelu(fs1.y + fdv.y) * at.y +
                   lrelu(fs1.z + fdv.z) * at.z + lrelu(fs1.w + fdv.w) * at.w;
        v0 += __shfl_xor(v0, 1);  v1 += __shfl_xor(v1, 1);
        v0 += __shfl_xor(v0, 2);  v1 += __shfl_xor(v1, 2);
        v0 += __shfl_xor(v0, 4);  v1 += __shfl_xor(v1, 4);
        float w0 = (e0 < end) ? __expf(v0 - K) : 0.f;
        float w1 = (e1 < end) ? __expf(v1 - K) : 0.f;
        acc.x += fs0.x * w0 + fs1.x * w1;
        acc.y += fs0.y * w0 + fs1.y * w1;
        acc.z += fs0.z * w0 + fs1.z * w1;
        acc.w += fs0.w * w0 + fs1.w * w1;
        den += w0 + w1;
    }
#pragma unroll
    for (int off = 8; off <= 32; off <<= 1) {
        acc.x += __shfl_xor(acc.x, off);
        acc.y += __shfl_xor(acc.y, off);
        acc.z += __shfl_xor(acc.z, off);
        acc.w += __shfl_xor(acc.w, off);
        den   += __shfl_xor(den, off);
    }
    if (g == 0) {
        float inv = 1.f / (den > 0.f ? den : 1.f);
        ((float4*)out)[(size_t)wave * 8 + q] =
            make_float4(acc.x * inv, acc.y * inv, acc.z * inv, acc.w * inv);
    }
}

extern "C" void kernel_launch(void* const* d_in, const int* in_sizes, int n_in,
                              void* d_out, int out_size, void* d_ws, size_t ws_size,
                              hipStream_t stream) {
    const void* u     = d_in[0];
    const void* lmax  = d_in[1];
    const int*  esrc  = (const int*)d_in[2];
    const int*  edst  = (const int*)d_in[3];
    const void* chebW = d_in[4];
    const void* chebB = d_in[5];
    const void* srcW  = d_in[6];
    const void* srcB  = d_in[7];
    const void* dstW  = d_in[8];
    const void* dstB  = d_in[9];
    const void* attn  = d_in[10];

    const int ND = in_sizes[0];   // N*32
    const int N  = ND / DD;
    const int E  = in_sizes[2];

    const int NB1 = (N + CB_NODES - 1) >> CB_SHIFT;     // 391
    const int T   = (E + TILE - 1) / TILE;              // 391
    const int M   = NB1 * T;

    // ws layout (~47 MB):
    //  ub[ND bf16] | X1b[ND bf16](->fsrcb) | X2b[ND bf16] | fd[ND f32]
    //  | tmp[E u32] | srcs[E] | hist1[M] | row_ptr[N+1] | dinv[N]
    //  | bsum[NB1] | wsW | flags | Mabs[32]
    u16* ub   = (u16*)d_ws;
    u16* X1b  = ub + (size_t)ND;
    u16* X2b  = X1b + (size_t)ND;
    float* fd = (float*)(X2b + (size_t)ND);
    unsigned* tmp = (unsigned*)(fd + (size_t)ND);
    int*   srcs = (int*)(tmp + E);
    unsigned* hist1   = (unsigned*)(srcs + E);
    unsigned* row_ptr = hist1 + M;
    float*    dinv    = (float*)(row_ptr + (N + 1));
    unsigned* bsum    = (unsigned*)(dinv + N);
    float*    wsW     = (float*)(((uintptr_t)(bsum + NB1) + 15) & ~(uintptr_t)15);
    int*      flags   = (int*)(wsW + W_TOTAL);
    unsigned* Mabs    = (unsigned*)(((uintptr_t)(flags + N_FLAGS) + 15) & ~(uintptr_t)15);
    float*    out     = (float*)d_out;

    auto gb = [](long long n, int b) { return (unsigned)((n + b - 1) / b); };

    k_detect<<<N_FLAGS, 64, 0, stream>>>(u, chebW, chebB, srcW, srcB, dstW, dstB,
                                         attn, lmax, ND, DD, flags);
    k_cvtw<<<gb(W_TOTAL + 32, BLK), BLK, 0, stream>>>(chebW, chebB, srcW, srcB,
                                                      dstW, dstB, attn, lmax,
                                                      flags, wsW, Mabs);
    k_cvtu<<<gb(ND, BLK), BLK, 0, stream>>>(u, flags, ub, ND);

    // two-level counting sort -> srcs (CSR payload), row_ptr, dinv
    k_h1<<<T, BLK, 0, stream>>>(edst, hist1, E, T, NB1);
    k_scA<<<NB1, BLK, 0, stream>>>(hist1, bsum, T);
    k_scB<<<1, 512, 0, stream>>>(bsum, NB1, row_ptr, N, E);
    k_s1<<<T, BLK, 0, stream>>>(esrc, edst, hist1, bsum, tmp, E, T, NB1);
    k_p2<<<NB1, BLK, 0, stream>>>(tmp, bsum, row_ptr, dinv, srcs, N, E, T, NB1);

    // Chebyshev recursion via per-node gathers (bf16 tables)
    k_unnl1<<<gb((long long)N * 64, BLK), BLK, 0, stream>>>(ub, u, flags, dinv,
                                                            row_ptr, srcs, wsW, X1b, N);
    k_unnl2<<<gb((long long)N * 64, BLK), BLK, 0, stream>>>(X1b, u, flags, dinv,
                                                            row_ptr, srcs, wsW, X2b, N);

    // fused cheb + projections (fsrcb aliases X1b; fdst -> fd f32; Mabs bound)
    k_cfsd<<<gb(N, BLK), BLK, 0, stream>>>(u, flags, X1b, X2b, wsW, X1b, fd, Mabs, N);

    // fused GATv2 (single pass, bound-shifted softmax, bf16 fsrc gather)
    k_gat<<<gb((long long)N * 64, BLK), BLK, 0, stream>>>(X1b, fd, row_ptr, srcs,
                                                          wsW, Mabs, out, N);
}

// Round 14
// 287.492 us; speedup vs baseline: 1.0095x; 1.0095x over previous
//
#include <hip/hip_runtime.h>
#include <hip/hip_bf16.h>

// SpectralAttentionLayer: ChebConv(K=3) -> relu -> GATv2(heads=1)
// N=100000, E=1600000, D=32.  All float inputs f32 (device detector kept as
// insurance), output f32.
// Round-14: gather kernels are issue/latency bound (r13: FETCH -26% at flat
// time).  Remove the random dinv[s] load stream from the unnl loops by
// pre-scaling the gather tables: ubs = bf16(u*dinv), X1s = bf16(X1*dinv)
// (written by unnl1 epilogue).  Halves random line requests per unnl
// iteration and drops 4 loads + addr-calcs per lane.

typedef unsigned short u16;

#define DD 32
#define NEG_SLOPE 0.2f
#define BLK 256
#define TILE 4096            // edges per pass-1 tile
#define CB_SHIFT 8           // coarse bucket = dst >> 8 (256 nodes)
#define CB_NODES 256
#define SRC_BITS 17          // N=100000 < 2^17

// weight block offsets inside wsW (floats)
#define OFF_CHEBW 0      // 3072
#define OFF_CHEBB 3072   // 32
#define OFF_SRCW  3104   // 1024
#define OFF_SRCB  4128   // 32
#define OFF_DSTW  4160   // 1024
#define OFF_DSTB  5184   // 32
#define OFF_ATTN  5216   // 32
#define OFF_LMAX  5248   // 1
#define W_TOTAL   5249

// flags indices (1 = f32 storage, 0 = bf16 storage)
#define F_U     0
#define F_CHEBW 1
#define F_CHEBB 2
#define F_SRCW  3
#define F_SRCB  4
#define F_DSTW  5
#define F_DSTB  6
#define F_ATTN  7
#define F_LMAX  8
#define N_FLAGS 9

__device__ __forceinline__ float bh2f(u16 h) {
    return __uint_as_float(((unsigned)h) << 16);
}
// round-to-nearest-even f32 -> bf16 bits
__device__ __forceinline__ u16 f2b(float v) {
    unsigned x = __float_as_uint(v);
    return (u16)((x + 0x7FFFu + ((x >> 16) & 1u)) >> 16);
}
__device__ __forceinline__ float rdin(const void* p, long long i, int f32f) {
    return f32f ? ((const float*)p)[i] : bh2f(((const u16*)p)[i]);
}
__device__ __forceinline__ float4 rd4(const void* p, long long row, int q, int f32f) {
    if (f32f) return ((const float4*)p)[row * 8 + q];
    ushort4 h = ((const ushort4*)p)[row * 8 + q];
    return make_float4(bh2f(h.x), bh2f(h.y), bh2f(h.z), bh2f(h.w));
}
// bf16 row table: float4 group q (dims 4q..4q+3) of row
__device__ __forceinline__ float4 rb4(const u16* p, long long row, int q) {
    ushort4 h = ((const ushort4*)p)[row * 8 + q];
    return make_float4(bh2f(h.x), bh2f(h.y), bh2f(h.z), bh2f(h.w));
}
__device__ __forceinline__ ushort4 pk4(float a, float b, float c, float d) {
    ushort4 r; r.x = f2b(a); r.y = f2b(b); r.z = f2b(c); r.w = f2b(d);
    return r;
}
__device__ __forceinline__ float lrelu(float x) { return fmaxf(x, NEG_SLOPE * x); }

__device__ __forceinline__ int plaus(u16 h) {
    if ((h & 0x7FFFu) == 0) return 1;
    unsigned e = (h >> 7) & 0xFF;
    return (e >= 0x60 && e <= 0x8F) ? 1 : 0;
}

// one block per array; 64 threads vote on even halfwords
__global__ void k_detect(const void* p0, const void* p1, const void* p2,
                         const void* p3, const void* p4, const void* p5,
                         const void* p6, const void* p7, const void* p8,
                         int n0, int n7, int* __restrict__ flags) {
    __shared__ int cEven, cEvenZ, cOddNZ;
    const void* ptrs[N_FLAGS] = {p0, p1, p2, p3, p4, p5, p6, p7, p8};
    const int   ns[N_FLAGS]   = {n0, 3072, 32, 1024, 32, 1024, 32, n7, 1};
    int a = blockIdx.x;
    if (a >= N_FLAGS) return;
    const u16* h = (const u16*)ptrs[a];
    int n = ns[a];
    if (threadIdx.x == 0) { cEven = 0; cEvenZ = 0; cOddNZ = 0; }
    __syncthreads();
    if (n == 1) {
        if (threadIdx.x == 0) {
            u16 v = h[0];
            flags[a] = ((v & 0x7FFFu) == 0 || !plaus(v)) ? 1 : 0;
        }
        return;
    }
    int nprobe = n >> 1;
    if (nprobe > 64) nprobe = 64;
    int t = threadIdx.x;
    if (t < nprobe) {
        u16 ev = h[2 * t];
        u16 od = h[2 * t + 1];
        if (plaus(ev)) atomicAdd(&cEven, 1);
        if ((ev & 0x7FFFu) == 0) atomicAdd(&cEvenZ, 1);
        if (plaus(od) && (od & 0x7FFFu) != 0) atomicAdd(&cOddNZ, 1);
    }
    __syncthreads();
    if (threadIdx.x == 0) {
        int bf = (cEven * 4 >= nprobe * 3);
        if (cEvenZ == nprobe && cOddNZ * 2 >= nprobe) bf = 0;
        flags[a] = bf ? 0 : 1;
    }
}

// converts weights into fp32 wsW; also zeroes Mabs (last 32 slots)
__global__ void k_cvtw(const void* chebW, const void* chebB, const void* srcW,
                       const void* srcB, const void* dstW, const void* dstB,
                       const void* attn, const void* lmax,
                       const int* __restrict__ flags, float* __restrict__ wsW,
                       unsigned* __restrict__ Mabs) {
    int i = blockIdx.x * blockDim.x + threadIdx.x;
    if (i >= W_TOTAL + 32) return;
    if (i >= W_TOTAL) { Mabs[i - W_TOTAL] = 0u; return; }
    float v;
    if      (i < OFF_CHEBB) v = rdin(chebW, i - OFF_CHEBW, flags[F_CHEBW]);
    else if (i < OFF_SRCW)  v = rdin(chebB, i - OFF_CHEBB, flags[F_CHEBB]);
    else if (i < OFF_SRCB)  v = rdin(srcW,  i - OFF_SRCW,  flags[F_SRCW]);
    else if (i < OFF_DSTW)  v = rdin(srcB,  i - OFF_SRCB,  flags[F_SRCB]);
    else if (i < OFF_DSTB)  v = rdin(dstW,  i - OFF_DSTW,  flags[F_DSTW]);
    else if (i < OFF_ATTN)  v = rdin(dstB,  i - OFF_DSTB,  flags[F_DSTB]);
    else if (i < OFF_LMAX)  v = rdin(attn,  i - OFF_ATTN,  flags[F_ATTN]);
    else                    v = rdin(lmax,  0,             flags[F_LMAX]);
    wsW[i] = v;
}

// u*dinv -> bf16 pre-scaled gather table (run AFTER k_p2 produces dinv)
__global__ void k_cvtus(const void* __restrict__ u, const int* __restrict__ flags,
                        const float* __restrict__ dinv, u16* __restrict__ ubs,
                        int ND) {
    int i = blockIdx.x * blockDim.x + threadIdx.x;
    if (i < ND) ubs[i] = f2b(rdin(u, i, flags[F_U]) * dinv[i >> 5]);
}

// ---------------- two-level counting sort ----------------

__global__ __launch_bounds__(BLK) void k_h1(
        const int* __restrict__ dst, unsigned* __restrict__ hist1,
        int E, int T, int NB1) {
    __shared__ unsigned lh[512];
    int tile = blockIdx.x, t = threadIdx.x;
    for (int b = t; b < 512; b += BLK) lh[b] = 0;
    __syncthreads();
    int base = tile * TILE;
    for (int i = 0; i < TILE / BLK; i++) {
        int e = base + i * BLK + t;
        if (e < E) atomicAdd(&lh[dst[e] >> CB_SHIFT], 1u);
    }
    __syncthreads();
    for (int b = t; b < NB1; b += BLK) hist1[(size_t)b * T + tile] = lh[b];
}

__global__ __launch_bounds__(BLK) void k_scA(
        unsigned* __restrict__ h, unsigned* __restrict__ bsum, int T) {
    __shared__ unsigned s[BLK];
    int b = blockIdx.x, t = threadIdx.x;
    unsigned carry = 0;
    for (int base = 0; base < T; base += BLK) {
        int i = base + t;
        unsigned v = (i < T) ? h[(size_t)b * T + i] : 0u;
        s[t] = v;
        __syncthreads();
        for (int off = 1; off < BLK; off <<= 1) {
            unsigned a = (t >= off) ? s[t - off] : 0u;
            __syncthreads();
            s[t] += a;
            __syncthreads();
        }
        if (i < T) h[(size_t)b * T + i] = carry + s[t] - v;
        carry += s[BLK - 1];
        __syncthreads();
    }
    if (t == 0) bsum[b] = carry;
}

__global__ __launch_bounds__(512) void k_scB(
        unsigned* __restrict__ bsum, int NB1,
        unsigned* __restrict__ row_ptr, int N, int E) {
    __shared__ unsigned s[512];
    int t = threadIdx.x;
    unsigned v = (t < NB1) ? bsum[t] : 0u;
    s[t] = v;
    __syncthreads();
    for (int off = 1; off < 512; off <<= 1) {
        unsigned a = (t >= off) ? s[t - off] : 0u;
        __syncthreads();
        s[t] += a;
        __syncthreads();
    }
    if (t < NB1) bsum[t] = s[t] - v;
    if (t == 0) row_ptr[N] = (unsigned)E;
}

__global__ __launch_bounds__(BLK) void k_s1(
        const int* __restrict__ src, const int* __restrict__ dst,
        const unsigned* __restrict__ off1, const unsigned* __restrict__ bsum,
        unsigned* __restrict__ tmp, int E, int T, int NB1) {
    __shared__ unsigned cur[512];
    int tile = blockIdx.x, t = threadIdx.x;
    for (int b = t; b < NB1; b += BLK)
        cur[b] = off1[(size_t)b * T + tile] + bsum[b];
    __syncthreads();
    int base = tile * TILE;
    for (int i = 0; i < TILE / BLK; i++) {
        int e = base + i * BLK + t;
        if (e < E) {
            int d = dst[e];
            unsigned pos = atomicAdd(&cur[d >> CB_SHIFT], 1u);
            tmp[pos] = ((unsigned)(d & (CB_NODES - 1)) << SRC_BITS) | (unsigned)src[e];
        }
    }
}

__global__ __launch_bounds__(BLK) void k_p2(
        const unsigned* __restrict__ tmp, const unsigned* __restrict__ bsum,
        unsigned* __restrict__ row_ptr, float* __restrict__ dinv,
        int* __restrict__ srcs, int N, int E, int T, int NB1) {
    __shared__ unsigned hist[CB_NODES], cur[CB_NODES], ssc[BLK];
    int b = blockIdx.x, t = threadIdx.x;
    int nodeBase = b << CB_SHIFT;
    unsigned lo = bsum[b];
    unsigned hi = (b + 1 < NB1) ? bsum[b + 1] : (unsigned)E;
    hist[t] = 0;
    __syncthreads();
    for (unsigned e = lo + t; e < hi; e += BLK)
        atomicAdd(&hist[tmp[e] >> SRC_BITS], 1u);
    __syncthreads();
    unsigned v = hist[t];
    ssc[t] = v;
    __syncthreads();
    for (int off = 1; off < BLK; off <<= 1) {
        unsigned a = (t >= off) ? ssc[t - off] : 0u;
        __syncthreads();
        ssc[t] += a;
        __syncthreads();
    }
    unsigned ex = ssc[t] - v;
    cur[t] = ex;
    int node = nodeBase + t;
    if (node < N) {
        row_ptr[node] = lo + ex;
        unsigned c = v;
        if (c < 1u) c = 1u;
        dinv[node] = rsqrtf((float)c);
    }
    __syncthreads();
    for (unsigned e = lo + t; e < hi; e += BLK) {
        unsigned p = tmp[e];
        unsigned pos = lo + atomicAdd(&cur[p >> SRC_BITS], 1u);
        srcs[pos] = (int)(p & ((1u << SRC_BITS) - 1u));
    }
}

// ---------------- wave-per-node gather kernels (pre-scaled bf16) -----------

// X1 = -rn*sum(ubs[s]) + u*(rn-1); writes X1b (unscaled) and X1s (=X1*dinv)
__global__ __launch_bounds__(BLK) void k_unnl1(
        const u16* __restrict__ ubs, const void* __restrict__ u,
        const int* __restrict__ flags, const float* __restrict__ dinv,
        const unsigned* __restrict__ row_ptr, const int* __restrict__ srcs,
        const float* __restrict__ wsW, u16* __restrict__ X1b,
        u16* __restrict__ X1s, int N) {
    int wave = (blockIdx.x * BLK + threadIdx.x) >> 6;
    if (wave >= N) return;
    int lane = threadIdx.x & 63, q = lane & 7, g = lane >> 3;
    int base = (int)row_ptr[wave], end = (int)row_ptr[wave + 1];
    float4 acc = make_float4(0.f, 0.f, 0.f, 0.f);
    for (int i = base; i < end; i += 32) {
        int e0 = i + g, e1 = i + 8 + g, e2 = i + 16 + g, e3 = i + 24 + g;
        int s0 = srcs[min(e0, end - 1)], s1 = srcs[min(e1, end - 1)];
        int s2 = srcs[min(e2, end - 1)], s3 = srcs[min(e3, end - 1)];
        float w0 = (e0 < end) ? 1.f : 0.f;
        float w1 = (e1 < end) ? 1.f : 0.f;
        float w2 = (e2 < end) ? 1.f : 0.f;
        float w3 = (e3 < end) ? 1.f : 0.f;
        float4 x0 = rb4(ubs, s0, q);
        float4 x1 = rb4(ubs, s1, q);
        float4 x2 = rb4(ubs, s2, q);
        float4 x3 = rb4(ubs, s3, q);
        acc.x += x0.x * w0 + x1.x * w1 + x2.x * w2 + x3.x * w3;
        acc.y += x0.y * w0 + x1.y * w1 + x2.y * w2 + x3.y * w3;
        acc.z += x0.z * w0 + x1.z * w1 + x2.z * w2 + x3.z * w3;
        acc.w += x0.w * w0 + x1.w * w1 + x2.w * w2 + x3.w * w3;
    }
#pragma unroll
    for (int off = 8; off <= 32; off <<= 1) {
        acc.x += __shfl_xor(acc.x, off);
        acc.y += __shfl_xor(acc.y, off);
        acc.z += __shfl_xor(acc.z, off);
        acc.w += __shfl_xor(acc.w, off);
    }
    if (g == 0) {
        float rn = 2.0f / wsW[OFF_LMAX];
        float dn = dinv[wave];
        float4 x0 = rd4(u, wave, q, flags[F_U]);    // f32 input for precision
        float vx = -rn * (acc.x * dn) + x0.x * (rn - 1.f);
        float vy = -rn * (acc.y * dn) + x0.y * (rn - 1.f);
        float vz = -rn * (acc.z * dn) + x0.z * (rn - 1.f);
        float vw = -rn * (acc.w * dn) + x0.w * (rn - 1.f);
        ((ushort4*)X1b)[(size_t)wave * 8 + q] = pk4(vx, vy, vz, vw);
        ((ushort4*)X1s)[(size_t)wave * 8 + q] =
            pk4(vx * dn, vy * dn, vz * dn, vw * dn);
    }
}

// X2 = -2rn*sum(X1s[s]) + X1*2(rn-1) - X0
__global__ __launch_bounds__(BLK) void k_unnl2(
        const u16* __restrict__ X1s, const u16* __restrict__ X1b,
        const void* __restrict__ u, const int* __restrict__ flags,
        const float* __restrict__ dinv, const unsigned* __restrict__ row_ptr,
        const int* __restrict__ srcs, const float* __restrict__ wsW,
        u16* __restrict__ X2b, int N) {
    int wave = (blockIdx.x * BLK + threadIdx.x) >> 6;
    if (wave >= N) return;
    int lane = threadIdx.x & 63, q = lane & 7, g = lane >> 3;
    int base = (int)row_ptr[wave], end = (int)row_ptr[wave + 1];
    float4 acc = make_float4(0.f, 0.f, 0.f, 0.f);
    for (int i = base; i < end; i += 32) {
        int e0 = i + g, e1 = i + 8 + g, e2 = i + 16 + g, e3 = i + 24 + g;
        int s0 = srcs[min(e0, end - 1)], s1 = srcs[min(e1, end - 1)];
        int s2 = srcs[min(e2, end - 1)], s3 = srcs[min(e3, end - 1)];
        float w0 = (e0 < end) ? 1.f : 0.f;
        float w1 = (e1 < end) ? 1.f : 0.f;
        float w2 = (e2 < end) ? 1.f : 0.f;
        float w3 = (e3 < end) ? 1.f : 0.f;
        float4 x0 = rb4(X1s, s0, q);
        float4 x1 = rb4(X1s, s1, q);
        float4 x2 = rb4(X1s, s2, q);
        float4 x3 = rb4(X1s, s3, q);
        acc.x += x0.x * w0 + x1.x * w1 + x2.x * w2 + x3.x * w3;
        acc.y += x0.y * w0 + x1.y * w1 + x2.y * w2 + x3.y * w3;
        acc.z += x0.z * w0 + x1.z * w1 + x2.z * w2 + x3.z * w3;
        acc.w += x0.w * w0 + x1.w * w1 + x2.w * w2 + x3.w * w3;
    }
#pragma unroll
    for (int off = 8; off <= 32; off <<= 1) {
        acc.x += __shfl_xor(acc.x, off);
        acc.y += __shfl_xor(acc.y, off);
        acc.z += __shfl_xor(acc.z, off);
        acc.w += __shfl_xor(acc.w, off);
    }
    if (g == 0) {
        float rn = 2.0f / wsW[OFF_LMAX];
        float dn = dinv[wave];
        float4 x0 = rd4(u, wave, q, flags[F_U]);
        float4 x1 = rb4(X1b, wave, q);
        ((ushort4*)X2b)[(size_t)wave * 8 + q] =
            pk4(-2.f * rn * (acc.x * dn) + x1.x * (2.f * (rn - 1.f)) - x0.x,
                -2.f * rn * (acc.y * dn) + x1.y * (2.f * (rn - 1.f)) - x0.y,
                -2.f * rn * (acc.z * dn) + x1.z * (2.f * (rn - 1.f)) - x0.z,
                -2.f * rn * (acc.w * dn) + x1.w * (2.f * (rn - 1.f)) - x0.w);
    }
}

// ---------------- fused cheb + projections, node-per-thread ----------------
// fsrcb (bf16) aliases X1s (dead after unnl2).  fdst -> f32 buffer.
__global__ __launch_bounds__(BLK) void k_cfsd(
        const void* __restrict__ u, const int* __restrict__ flags,
        const u16* X1b, const u16* X2b,
        const float* __restrict__ wsW, u16* fsrcb,
        float* __restrict__ fd, unsigned* __restrict__ Mabs, int N) {
    __shared__ float sW[3072], sWs[1024], sWd[1024];
    __shared__ float sb[32], sbs[32], sbd[32];
    __shared__ float hcS[BLK * 33];          // pad 33 -> conflict-free
    __shared__ unsigned mloc[32];
    int t = threadIdx.x;
    for (int i = t; i < 3072; i += BLK) sW[i] = wsW[OFF_CHEBW + i];
    for (int i = t; i < 1024; i += BLK) {
        sWs[i] = wsW[OFF_SRCW + i];
        sWd[i] = wsW[OFF_DSTW + i];
    }
    if (t < 32) {
        sb[t]  = wsW[OFF_CHEBB + t];
        sbs[t] = wsW[OFF_SRCB + t];
        sbd[t] = wsW[OFF_DSTB + t];
        mloc[t] = 0u;
    }
    __syncthreads();
    int f = flags[F_U];
    float mabs = 0.f;
    int n = blockIdx.x * BLK + t;
    if (n < N) {
        long long row = (long long)n;
        float acc[32];
#pragma unroll
        for (int j = 0; j < 32; j++) acc[j] = sb[j];
        for (int i4 = 0; i4 < 8; i4++) {
            float4 x = rd4(u, row, i4, f);
            const float* w = &sW[i4 * 128];
#pragma unroll
            for (int j = 0; j < 32; j++) acc[j] = fmaf(x.x, w[j], acc[j]);
#pragma unroll
            for (int j = 0; j < 32; j++) acc[j] = fmaf(x.y, w[32 + j], acc[j]);
#pragma unroll
            for (int j = 0; j < 32; j++) acc[j] = fmaf(x.z, w[64 + j], acc[j]);
#pragma unroll
            for (int j = 0; j < 32; j++) acc[j] = fmaf(x.w, w[96 + j], acc[j]);
        }
        for (int i4 = 0; i4 < 8; i4++) {
            float4 x = rb4(X1b, row, i4);
            const float* w = &sW[1024 + i4 * 128];
#pragma unroll
            for (int j = 0; j < 32; j++) acc[j] = fmaf(x.x, w[j], acc[j]);
#pragma unroll
            for (int j = 0; j < 32; j++) acc[j] = fmaf(x.y, w[32 + j], acc[j]);
#pragma unroll
            for (int j = 0; j < 32; j++) acc[j] = fmaf(x.z, w[64 + j], acc[j]);
#pragma unroll
            for (int j = 0; j < 32; j++) acc[j] = fmaf(x.w, w[96 + j], acc[j]);
        }
        for (int i4 = 0; i4 < 8; i4++) {
            float4 x = rb4(X2b, row, i4);
            const float* w = &sW[2048 + i4 * 128];
#pragma unroll
            for (int j = 0; j < 32; j++) acc[j] = fmaf(x.x, w[j], acc[j]);
#pragma unroll
            for (int j = 0; j < 32; j++) acc[j] = fmaf(x.y, w[32 + j], acc[j]);
#pragma unroll
            for (int j = 0; j < 32; j++) acc[j] = fmaf(x.z, w[64 + j], acc[j]);
#pragma unroll
            for (int j = 0; j < 32; j++) acc[j] = fmaf(x.w, w[96 + j], acc[j]);
        }
#pragma unroll
        for (int j = 0; j < 32; j++) hcS[t * 33 + j] = fmaxf(acc[j], 0.f);
        float as[32], ad[32];
#pragma unroll
        for (int j = 0; j < 32; j++) { as[j] = sbs[j]; ad[j] = sbd[j]; }
        for (int i = 0; i < 32; i++) {
            float hv = hcS[t * 33 + i];
            const float* ws = &sWs[i * 32];
            const float* wd = &sWd[i * 32];
#pragma unroll
            for (int j = 0; j < 32; j++) {
                as[j] = fmaf(hv, ws[j], as[j]);
                ad[j] = fmaf(hv, wd[j], ad[j]);
            }
        }
        ushort4* fs4 = (ushort4*)(fsrcb + row * 32);
        float4*  fd4 = (float4*)(fd + row * 32);
#pragma unroll
        for (int i4 = 0; i4 < 8; i4++) {
            fs4[i4] = pk4(as[4 * i4], as[4 * i4 + 1], as[4 * i4 + 2], as[4 * i4 + 3]);
            fd4[i4] = make_float4(ad[4 * i4], ad[4 * i4 + 1], ad[4 * i4 + 2], ad[4 * i4 + 3]);
        }
#pragma unroll
        for (int j = 0; j < 32; j++) mabs = fmaxf(mabs, fabsf(as[j]));
    }
    // mabs = node max over all dims; per-dim max <= this, so K from Mabs
    // stays a valid upper bound (1.01 covers bf16 round-up of fsrc).
    atomicMax(&mloc[t & 31], __float_as_uint(mabs * 1.01f));
    __syncthreads();
    if (t < 32) atomicMax(&Mabs[t], mloc[t]);
}

// ---------------- fused GATv2, bound-shifted softmax, single pass ----------
__global__ __launch_bounds__(BLK) void k_gat(
        const u16* __restrict__ fsrcb, const float* __restrict__ fd,
        const unsigned* __restrict__ row_ptr, const int* __restrict__ srcs,
        const float* __restrict__ wsW, const unsigned* __restrict__ Mabs,
        float* __restrict__ out, int N) {
    int wave = (blockIdx.x * BLK + threadIdx.x) >> 6;
    if (wave >= N) return;
    int lane = threadIdx.x & 63, q = lane & 7, g = lane >> 3;
    int base = (int)row_ptr[wave], end = (int)row_ptr[wave + 1];
    if (base == end) {
        if (g == 0)
            ((float4*)out)[(size_t)wave * 8 + q] = make_float4(0.f, 0.f, 0.f, 0.f);
        return;
    }
    float4 fdv = ((const float4*)fd)[(size_t)wave * 8 + q];
    float4 at = ((const float4*)(wsW + OFF_ATTN))[q];
    float4 mb = ((const float4*)Mabs)[q];   // bits of nonneg floats
    float kp = (mb.x + fabsf(fdv.x)) * fabsf(at.x) +
               (mb.y + fabsf(fdv.y)) * fabsf(at.y) +
               (mb.z + fabsf(fdv.z)) * fabsf(at.z) +
               (mb.w + fabsf(fdv.w)) * fabsf(at.w);
    kp += __shfl_xor(kp, 1);
    kp += __shfl_xor(kp, 2);
    kp += __shfl_xor(kp, 4);
    float K = kp;
    float4 acc = make_float4(0.f, 0.f, 0.f, 0.f);
    float den = 0.f;
    for (int i = base; i < end; i += 16) {
        int e0 = i + g, e1 = i + 8 + g;
        int ec0 = min(e0, end - 1), ec1 = min(e1, end - 1);
        int s0 = srcs[ec0], s1 = srcs[ec1];
        float4 fs0 = rb4(fsrcb, s0, q);
        float4 fs1 = rb4(fsrcb, s1, q);
        float v0 = lrelu(fs0.x + fdv.x) * at.x + lrelu(fs0.y + fdv.y) * at.y +
                   lrelu(fs0.z + fdv.z) * at.z + lrelu(fs0.w + fdv.w) * at.w;
        float v1 = lrelu(fs1.x + fdv.x) * at.x + lrelu(fs1.y + fdv.y) * at.y +
                   lrelu(fs1.z + fdv.z) * at.z + lrelu(fs1.w + fdv.w) * at.w;
        v0 += __shfl_xor(v0, 1);  v1 += __shfl_xor(v1, 1);
        v0 += __shfl_xor(v0, 2);  v1 += __shfl_xor(v1, 2);
        v0 += __shfl_xor(v0, 4);  v1 += __shfl_xor(v1, 4);
        float w0 = (e0 < end) ? __expf(v0 - K) : 0.f;
        float w1 = (e1 < end) ? __expf(v1 - K) : 0.f;
        acc.x += fs0.x * w0 + fs1.x * w1;
        acc.y += fs0.y * w0 + fs1.y * w1;
        acc.z += fs0.z * w0 + fs1.z * w1;
        acc.w += fs0.w * w0 + fs1.w * w1;
        den += w0 + w1;
    }
#pragma unroll
    for (int off = 8; off <= 32; off <<= 1) {
        acc.x += __shfl_xor(acc.x, off);
        acc.y += __shfl_xor(acc.y, off);
        acc.z += __shfl_xor(acc.z, off);
        acc.w += __shfl_xor(acc.w, off);
        den   += __shfl_xor(den, off);
    }
    if (g == 0) {
        float inv = 1.f / (den > 0.f ? den : 1.f);
        ((float4*)out)[(size_t)wave * 8 + q] =
            make_float4(acc.x * inv, acc.y * inv, acc.z * inv, acc.w * inv);
    }
}

extern "C" void kernel_launch(void* const* d_in, const int* in_sizes, int n_in,
                              void* d_out, int out_size, void* d_ws, size_t ws_size,
                              hipStream_t stream) {
    const void* u     = d_in[0];
    const void* lmax  = d_in[1];
    const int*  esrc  = (const int*)d_in[2];
    const int*  edst  = (const int*)d_in[3];
    const void* chebW = d_in[4];
    const void* chebB = d_in[5];
    const void* srcW  = d_in[6];
    const void* srcB  = d_in[7];
    const void* dstW  = d_in[8];
    const void* dstB  = d_in[9];
    const void* attn  = d_in[10];

    const int ND = in_sizes[0];   // N*32
    const int N  = ND / DD;
    const int E  = in_sizes[2];

    const int NB1 = (N + CB_NODES - 1) >> CB_SHIFT;     // 391
    const int T   = (E + TILE - 1) / TILE;              // 391
    const int M   = NB1 * T;

    // ws layout (~52 MB):
    //  ubs[ND bf16] | X1b[ND bf16] | X1s[ND bf16](->fsrcb) | X2b[ND bf16]
    //  | fd[ND f32] | tmp[E u32] | srcs[E] | hist1[M] | row_ptr[N+1]
    //  | dinv[N] | bsum[NB1] | wsW | flags | Mabs[32]
    u16* ubs  = (u16*)d_ws;
    u16* X1b  = ubs + (size_t)ND;
    u16* X1s  = X1b + (size_t)ND;
    u16* X2b  = X1s + (size_t)ND;
    float* fd = (float*)(X2b + (size_t)ND);
    unsigned* tmp = (unsigned*)(fd + (size_t)ND);
    int*   srcs = (int*)(tmp + E);
    unsigned* hist1   = (unsigned*)(srcs + E);
    unsigned* row_ptr = hist1 + M;
    float*    dinv    = (float*)(row_ptr + (N + 1));
    unsigned* bsum    = (unsigned*)(dinv + N);
    float*    wsW     = (float*)(((uintptr_t)(bsum + NB1) + 15) & ~(uintptr_t)15);
    int*      flags   = (int*)(wsW + W_TOTAL);
    unsigned* Mabs    = (unsigned*)(((uintptr_t)(flags + N_FLAGS) + 15) & ~(uintptr_t)15);
    float*    out     = (float*)d_out;

    auto gb = [](long long n, int b) { return (unsigned)((n + b - 1) / b); };

    k_detect<<<N_FLAGS, 64, 0, stream>>>(u, chebW, chebB, srcW, srcB, dstW, dstB,
                                         attn, lmax, ND, DD, flags);
    k_cvtw<<<gb(W_TOTAL + 32, BLK), BLK, 0, stream>>>(chebW, chebB, srcW, srcB,
                                                      dstW, dstB, attn, lmax,
                                                      flags, wsW, Mabs);

    // two-level counting sort -> srcs (CSR payload), row_ptr, dinv
    k_h1<<<T, BLK, 0, stream>>>(edst, hist1, E, T, NB1);
    k_scA<<<NB1, BLK, 0, stream>>>(hist1, bsum, T);
    k_scB<<<1, 512, 0, stream>>>(bsum, NB1, row_ptr, N, E);
    k_s1<<<T, BLK, 0, stream>>>(esrc, edst, hist1, bsum, tmp, E, T, NB1);
    k_p2<<<NB1, BLK, 0, stream>>>(tmp, bsum, row_ptr, dinv, srcs, N, E, T, NB1);

    // pre-scaled gather table (needs dinv)
    k_cvtus<<<gb(ND, BLK), BLK, 0, stream>>>(u, flags, dinv, ubs, ND);

    // Chebyshev recursion via per-node gathers (pre-scaled bf16 tables)
    k_unnl1<<<gb((long long)N * 64, BLK), BLK, 0, stream>>>(ubs, u, flags, dinv,
                                                            row_ptr, srcs, wsW,
                                                            X1b, X1s, N);
    k_unnl2<<<gb((long long)N * 64, BLK), BLK, 0, stream>>>(X1s, X1b, u, flags,
                                                            dinv, row_ptr, srcs,
                                                            wsW, X2b, N);

    // fused cheb + projections (fsrcb aliases X1s; fdst -> fd f32; Mabs bound)
    k_cfsd<<<gb(N, BLK), BLK, 0, stream>>>(u, flags, X1b, X2b, wsW, X1s, fd, Mabs, N);

    // fused GATv2 (single pass, bound-shifted softmax, bf16 fsrc gather)
    k_gat<<<gb((long long)N * 64, BLK), BLK, 0, stream>>>(X1s, fd, row_ptr, srcs,
                                                          wsW, Mabs, out, N);
}